// Round 13
// baseline (98.989 us; speedup 1.0000x reference)
//
#include <hip/hip_runtime.h>
#include <math.h>

namespace {
constexpr int B = 2;
constexpr int N = 16384;
constexpr int M = 4096;
constexpr int K = 11;
constexpr int TQ = 64;              // lanes per query group = full wave
constexpr int BLOCK = 1024;         // 16 waves/block
constexpr int Q = 8;                // queries per wave
constexpr int GROUPS = BLOCK / TQ;  // 16 waves/block
constexpr int QPB = GROUPS * Q;     // 128 queries/block -> 256 blocks = 1/CU
constexpr int S = M / TQ;           // 64 candidates per lane
constexpr int CAP = 48;             // per-query collect capacity (int2 entries)
}

typedef float v2f __attribute__((ext_vector_type(2)));

// LDS candidate record viewed as two VGPR pairs: (x,y) and (z,w=|s|^2).
struct __attribute__((aligned(16))) S2 { v2f xy; v2f zw; };

// Shifted squared distance for TWO queries at once via packed FP32 VOP3P.
// Slot q = fma(m2z_q, z, fma(m2y_q, y, fma(m2x_q, x, w))). (R12-validated.)
__device__ __forceinline__ v2f d2pair(S2 s, v2f m2x, v2f m2y, v2f m2z) {
  v2f acc;
  asm("v_pk_fma_f32 %0, %1, %2, %3 op_sel:[0,0,1] op_sel_hi:[0,1,1]"
      : "=v"(acc) : "v"(s.xy), "v"(m2x), "v"(s.zw));
  asm("v_pk_fma_f32 %0, %1, %2, %0 op_sel:[1,0,0] op_sel_hi:[1,1,1]"
      : "+v"(acc) : "v"(s.xy), "v"(m2y));
  asm("v_pk_fma_f32 %0, %1, %2, %0 op_sel:[0,0,0] op_sel_hi:[0,1,1]"
      : "+v"(acc) : "v"(s.zw), "v"(m2z));
  return acc;
}

// 112 KiB LDS/block -> 1 block/CU; 16 waves/CU = 4 waves/SIMD.
__global__ __launch_bounds__(BLOCK, 4) void voroloss_kernel(
    const float* __restrict__ points,    // [B, N, 3]
    const float* __restrict__ spoints,   // [B, M, 3]
    float* __restrict__ out)             // [B, N]
{
  __shared__ float4 s4[M];          // (x,y,z,|s|^2) 64 KiB
  __shared__ int2 buf2[QPB][CAP];   // (idx, d2 bits)  48 KiB

  const int blocks_per_batch = N / QPB;     // 128
  const int b = blockIdx.x / blocks_per_batch;
  const int tile = blockIdx.x % blocks_per_batch;
  const int tid = (int)threadIdx.x;
  const int wl = tid & 63;                  // lane in wave = lane in group
  const int g = tid >> 6;                   // wave id = group id (0..15)

  const float* sp = spoints + (size_t)b * M * 3;
  for (int j = tid; j < M; j += BLOCK) {
    float x = sp[j * 3 + 0], y = sp[j * 3 + 1], z = sp[j * 3 + 2];
    s4[j] = make_float4(x, y, z, x * x + y * y + z * z);
  }
  __syncthreads();
  const S2* s2 = (const S2*)s4;

  float m2x[Q], m2y[Q], m2z[Q];
#pragma unroll
  for (int q = 0; q < Q; ++q) {
    int n = tile * QPB + q * GROUPS + g;    // uniform per wave
    m2x[q] = -2.0f * points[((size_t)b * N + n) * 3 + 0];
    m2y[q] = -2.0f * points[((size_t)b * N + n) * 3 + 1];
    m2z[q] = -2.0f * points[((size_t)b * N + n) * 3 + 2];
  }
  // packed per-query-pair coefficients (slot0 = qp, slot1 = qp+1)
  v2f bmx[Q / 2], bmy[Q / 2], bmz[Q / 2];
#pragma unroll
  for (int p = 0; p < Q / 2; ++p) {
    bmx[p].x = m2x[2 * p]; bmx[p].y = m2x[2 * p + 1];
    bmy[p].x = m2y[2 * p]; bmy[p].y = m2y[2 * p + 1];
    bmz[p].x = m2z[2 * p]; bmz[p].y = m2z[2 * p + 1];
  }

  // ---- Phase A: per-lane min over strided subset j = i*64 + wl.
  float t0[Q];
#pragma unroll
  for (int q = 0; q < Q; ++q) t0[q] = INFINITY;

  for (int i0 = 0; i0 < S; i0 += 4) {
    S2 sv[4];
#pragma unroll
    for (int c = 0; c < 4; ++c) sv[c] = s2[(i0 + c) * TQ + wl];
#pragma unroll
    for (int p = 0; p < Q / 2; ++p) {
#pragma unroll
      for (int c = 0; c < 4; ++c) {
        v2f acc = d2pair(sv[c], bmx[p], bmy[p], bmz[p]);
        t0[2 * p]     = fminf(t0[2 * p],     acc.x);
        t0[2 * p + 1] = fminf(t0[2 * p + 1], acc.y);
      }
    }
  }

  // ---- theta: 11th smallest of 32 pair-minima per query (provable upper
  // bound on the true 11th smallest). Dual-query sorts: lower half-wave sorts
  // qp, upper half qp+1 (xor j<=16 never crosses the half boundary).
  const int h = wl & 31;
  bool km[15];
  {
    int st = 0;
#pragma unroll
    for (int k = 2; k <= 32; k <<= 1) {
#pragma unroll
      for (int j = 16; j > 0; j >>= 1) {
        if (j < k) {
          bool up = (h & k) == 0;
          bool lower = (h & j) == 0;
          km[st++] = (lower == up);
        }
      }
    }
  }
  float theta[Q];
#pragma unroll
  for (int qp = 0; qp < Q; qp += 2) {
    float a0 = fminf(t0[qp],     __shfl_xor(t0[qp],     32));
    float a1 = fminf(t0[qp + 1], __shfl_xor(t0[qp + 1], 32));
    float x = (wl < 32) ? a0 : a1;
    int st = 0;
#pragma unroll
    for (int k = 2; k <= 32; k <<= 1) {
#pragma unroll
      for (int j = 16; j > 0; j >>= 1) {
        if (j < k) {
          float o = __shfl_xor(x, j);
          x = km[st++] ? fminf(x, o) : fmaxf(x, o);
        }
      }
    }
    theta[qp]     = __shfl(x, 10, 64);
    theta[qp + 1] = __shfl(x, 42, 64);
  }

  // ---- Phase B: rescan; wave-cooperative compaction, SGPR counters, no
  // atomics. Stores (idx, d2bits) — d2 is the pk-computed value itself, so
  // Phase C compares are bit-exact by construction.
  int cnt[Q];
#pragma unroll
  for (int q = 0; q < Q; ++q) cnt[q] = 0;

  for (int i0 = 0; i0 < S; i0 += 4) {
    S2 sv[4];
#pragma unroll
    for (int c = 0; c < 4; ++c) sv[c] = s2[(i0 + c) * TQ + wl];
#pragma unroll
    for (int p = 0; p < Q / 2; ++p) {
#pragma unroll
      for (int c = 0; c < 4; ++c) {
        v2f acc = d2pair(sv[c], bmx[p], bmy[p], bmz[p]);
#pragma unroll
        for (int e = 0; e < 2; ++e) {
          const int q = 2 * p + e;
          float d = e ? acc.y : acc.x;
          bool hit = d <= theta[q];
          unsigned long long mask = __ballot(hit);
          if (mask != 0) {                  // uniform branch, rarely taken
            const int qq = q * GROUPS + g;
            int base = cnt[q];
            if (hit) {
              unsigned int lo = __builtin_amdgcn_mbcnt_lo((unsigned int)mask, 0u);
              unsigned int pr = __builtin_amdgcn_mbcnt_hi((unsigned int)(mask >> 32), lo);
              int pos = base + (int)pr;
              if (pos < CAP)
                buf2[qq][pos] = make_int2((i0 + c) * TQ + wl, __float_as_int(d));
            }
            cnt[q] = base + (int)__popcll(mask);
          }
        }
      }
    }
  }

  // ---- Phase C: exact selection (lex (d2,idx) = stable top_k). Lane wl owns
  // slot wl; ranks via UNIFORM broadcast reads (DS-cheap) + VALU compares.
#pragma unroll
  for (int q = 0; q < Q; ++q) {
    const int qq = q * GROUPS + g;
    int c = cnt[q];
    c = c < CAP ? c : CAP;

    bool v = wl < c;
    int2 e = buf2[qq][v ? wl : 0];          // strided b64: 2-way aliasing, free
    float d2e = v ? __int_as_float(e.y) : INFINITY;
    int ide = v ? e.x : 0x7fffffff;

    int rank = 0;
    for (int f = 0; f + 2 <= c; f += 2) {   // uniform b128 = 2 entries, broadcast
      int4 ee = *(const int4*)&buf2[qq][f];
      float d0 = __int_as_float(ee.y);
      float d1 = __int_as_float(ee.w);
      rank += ((d0 < d2e) || (d0 == d2e && ee.x < ide)) ? 1 : 0;
      rank += ((d1 < d2e) || (d1 == d2e && ee.z < ide)) ? 1 : 0;
    }
    if (c & 1) {                            // tail entry
      int2 et = buf2[qq][c - 1];
      float dt = __int_as_float(et.y);
      rank += ((dt < d2e) || (dt == d2e && et.x < ide)) ? 1 : 0;
    }

    // center = rank 0 (exists, unique): ballot + shfl its index.
    unsigned long long cb = __ballot(v && rank == 0);
    int cl = (int)__builtin_ctzll(cb);
    int ci = __shfl(ide, cl, 64);
    float4 cc = s4[ci];
    float px = -0.5f * m2x[q], py = -0.5f * m2y[q], pz = -0.5f * m2z[q];
    float vx = px - cc.x, vy = py - cc.y, vz = pz - cc.z;

    // edges = ranks 1..10 (exactly 10 since c >= 11).
    // sq = (dot(v,e) - |e|^2/2)^2 / |e|^2
    bool isedge = v && (rank >= 1) && (rank <= 10);
    float4 se = s4[isedge ? ide : 0];
    float ex = se.x - cc.x, ey = se.y - cc.y, ez = se.z - cc.z;
    float el2 = ex * ex;
    el2 = fmaf(ey, ey, el2);
    el2 = fmaf(ez, ez, el2);
    float dv = vx * ex;
    dv = fmaf(vy, ey, dv);
    dv = fmaf(vz, ez, dv);
    float tt = fmaf(-0.5f, el2, dv);
    float sq = tt * tt * __builtin_amdgcn_rcpf(el2);
    float best = isedge ? sq : INFINITY;
#pragma unroll
    for (int lvl = 1; lvl <= 32; lvl <<= 1) {
      best = fminf(best, __shfl_xor(best, lvl));
    }
    if (wl == 0) out[(size_t)b * N + (tile * QPB + q * GROUPS + g)] = best;
  }
}

extern "C" void kernel_launch(void* const* d_in, const int* in_sizes, int n_in,
                              void* d_out, int out_size, void* d_ws, size_t ws_size,
                              hipStream_t stream) {
  const float* points = (const float*)d_in[0];
  const float* spoints = (const float*)d_in[1];
  float* out = (float*)d_out;
  (void)in_sizes; (void)n_in; (void)out_size; (void)d_ws; (void)ws_size;
  voroloss_kernel<<<dim3(B * (N / QPB)), dim3(BLOCK), 0, stream>>>(points, spoints, out);
}

// Round 15
// 88.280 us; speedup vs baseline: 1.1213x; 1.1213x over previous
//
#include <hip/hip_runtime.h>
#include <math.h>

namespace {
constexpr int B = 2;
constexpr int N = 16384;
constexpr int M = 4096;
constexpr int TQ = 64;              // lanes per query group = full wave
constexpr int BLOCK = 1024;         // 16 waves/block
constexpr int Q = 4;                // queries per wave
constexpr int GROUPS = BLOCK / TQ;  // 16 waves/block
constexpr int QPB = GROUPS * Q;     // 64 queries/block -> 512 blocks = 2/CU
constexpr int S = M / TQ;           // 64 candidates per lane
constexpr int NB = 4;               // batches of 16 candidates per lane
constexpr int CAP = 48;             // per-query collect capacity
constexpr int CAPW = 256;           // per-wave worklist capacity (union <= 4*CAP = 192)
}

typedef float v2f __attribute__((ext_vector_type(2)));

// LDS candidate record viewed as two VGPR pairs: (x,y) and (z,w=|s|^2).
struct __attribute__((aligned(16))) S2 { v2f xy; v2f zw; };

// Shifted squared distance for TWO queries at once via packed FP32 VOP3P.
// Slot q = fma(m2z_q, z, fma(m2y_q, y, fma(m2x_q, x, w))). (R12-validated.)
// NOTE: values are shifted by -|p_q|^2 per query — comparable ONLY within a
// query. (R14 bug: cross-query thmax on shifted values -> worklist overflow.)
__device__ __forceinline__ v2f d2pair(S2 s, v2f m2x, v2f m2y, v2f m2z) {
  v2f acc;
  asm("v_pk_fma_f32 %0, %1, %2, %3 op_sel:[0,0,1] op_sel_hi:[0,1,1]"
      : "=v"(acc) : "v"(s.xy), "v"(m2x), "v"(s.zw));
  asm("v_pk_fma_f32 %0, %1, %2, %0 op_sel:[1,0,0] op_sel_hi:[1,1,1]"
      : "+v"(acc) : "v"(s.xy), "v"(m2y));
  asm("v_pk_fma_f32 %0, %1, %2, %0 op_sel:[0,0,0] op_sel_hi:[0,1,1]"
      : "+v"(acc) : "v"(s.zw), "v"(m2z));
  return acc;
}

// Scalar twin of d2pair's per-slot sequence — MUST match bit-exactly (Phase C).
__device__ __forceinline__ float d2of(const float4 s, float m2x, float m2y, float m2z) {
  return fmaf(m2z, s.z, fmaf(m2y, s.y, fmaf(m2x, s.x, s.w)));
}

// 78 KiB LDS/block, <=64 VGPR -> 2 blocks/CU, 32 waves/CU = 8 waves/SIMD
__global__ __launch_bounds__(BLOCK, 8) void voroloss_kernel(
    const float* __restrict__ points,    // [B, N, 3]
    const float* __restrict__ spoints,   // [B, M, 3]
    float* __restrict__ out)             // [B, N]
{
  __shared__ float4 s4[M];                         // (x,y,z,|s|^2) 64 KiB
  __shared__ unsigned short wl_lds[GROUPS][CAPW];  // per-wave worklist 8 KiB
  __shared__ unsigned short buf[QPB][CAP];         // candidate idx 6 KiB

  const int blocks_per_batch = N / QPB;      // 256
  const int b = blockIdx.x / blocks_per_batch;
  const int tile = blockIdx.x % blocks_per_batch;
  const int tid = (int)threadIdx.x;
  const int wl = tid & 63;                   // lane in wave = lane in group
  const int g = tid >> 6;                    // wave id = group id (0..15)

  const float* sp = spoints + (size_t)b * M * 3;
  for (int j = tid; j < M; j += BLOCK) {
    float x = sp[j * 3 + 0], y = sp[j * 3 + 1], z = sp[j * 3 + 2];
    s4[j] = make_float4(x, y, z, x * x + y * y + z * z);
  }
  __syncthreads();
  const S2* s2 = (const S2*)s4;

  float m2x[Q], m2y[Q], m2z[Q];
#pragma unroll
  for (int q = 0; q < Q; ++q) {
    int n = tile * QPB + q * GROUPS + g;     // uniform per wave
    m2x[q] = -2.0f * points[((size_t)b * N + n) * 3 + 0];
    m2y[q] = -2.0f * points[((size_t)b * N + n) * 3 + 1];
    m2z[q] = -2.0f * points[((size_t)b * N + n) * 3 + 2];
  }
  // packed per-query-pair coefficients (slot0 = qp, slot1 = qp+1)
  v2f bmx[2], bmy[2], bmz[2];
#pragma unroll
  for (int p = 0; p < 2; ++p) {
    bmx[p].x = m2x[2 * p]; bmx[p].y = m2x[2 * p + 1];
    bmy[p].x = m2y[2 * p]; bmy[p].y = m2y[2 * p + 1];
    bmz[p].x = m2z[2 * p]; bmz[p].y = m2z[2 * p + 1];
  }

  // ---- Phase A: PER-QUERY batch minima over 4 batches of 16 cands each.
  // bm2[p][bi] slot e = min d2 of query 2p+e over batch bi (pk values).
  v2f bm2[2][NB];
#pragma unroll
  for (int p = 0; p < 2; ++p)
#pragma unroll
    for (int bi = 0; bi < NB; ++bi) { bm2[p][bi].x = INFINITY; bm2[p][bi].y = INFINITY; }

#pragma unroll
  for (int bi = 0; bi < NB; ++bi) {
#pragma unroll
    for (int hf = 0; hf < 4; ++hf) {
      S2 sv[4];
#pragma unroll
      for (int c = 0; c < 4; ++c) sv[c] = s2[(bi * 16 + hf * 4 + c) * TQ + wl];
#pragma unroll
      for (int p = 0; p < 2; ++p) {
#pragma unroll
        for (int c = 0; c < 4; ++c) {
          v2f acc = d2pair(sv[c], bmx[p], bmy[p], bmz[p]);
          bm2[p][bi].x = fminf(bm2[p][bi].x, acc.x);
          bm2[p][bi].y = fminf(bm2[p][bi].y, acc.y);
        }
      }
    }
  }
  // per-lane minima derive from batch minima (no separate accumulators)
  float t0[Q];
#pragma unroll
  for (int p = 0; p < 2; ++p) {
    v2f m = bm2[p][0];
#pragma unroll
    for (int bi = 1; bi < NB; ++bi) {
      m.x = fminf(m.x, bm2[p][bi].x);
      m.y = fminf(m.y, bm2[p][bi].y);
    }
    t0[2 * p] = m.x; t0[2 * p + 1] = m.y;
  }

  // ---- theta: 11th smallest of 32 pair-minima per query (provable upper
  // bound on the true 11th smallest, within-query so shift cancels).
  const int h = wl & 31;
  bool km[15];
  {
    int st = 0;
#pragma unroll
    for (int k = 2; k <= 32; k <<= 1) {
#pragma unroll
      for (int j = 16; j > 0; j >>= 1) {
        if (j < k) {
          bool up = (h & k) == 0;
          bool lower = (h & j) == 0;
          km[st++] = (lower == up);
        }
      }
    }
  }
  float theta[Q];
#pragma unroll
  for (int qp = 0; qp < Q; qp += 2) {
    float a0 = fminf(t0[qp],     __shfl_xor(t0[qp],     32));
    float a1 = fminf(t0[qp + 1], __shfl_xor(t0[qp + 1], 32));
    float x = (wl < 32) ? a0 : a1;
    int st = 0;
#pragma unroll
    for (int k = 2; k <= 32; k <<= 1) {
#pragma unroll
      for (int j = 16; j > 0; j >>= 1) {
        if (j < k) {
          float o = __shfl_xor(x, j);
          x = km[st++] ? fminf(x, o) : fmaxf(x, o);
        }
      }
    }
    theta[qp]     = __shfl(x, 10, 64);
    theta[qp + 1] = __shfl(x, 42, 64);
  }

  // ---- Worklist: batches with ANY per-query hit (bm_q <= theta_q, exact
  // within-query comparison). |worklist| <= sum_q #{d_q <= theta_q} <= 192.
  int wcnt = 0;
#pragma unroll
  for (int bi = 0; bi < NB; ++bi) {
    bool hit = (bm2[0][bi].x <= theta[0]) || (bm2[0][bi].y <= theta[1]) ||
               (bm2[1][bi].x <= theta[2]) || (bm2[1][bi].y <= theta[3]);
    unsigned long long mask = __ballot(hit);
    if (mask != 0) {
      if (hit) {
        unsigned int lo = __builtin_amdgcn_mbcnt_lo((unsigned int)mask, 0u);
        unsigned int pr = __builtin_amdgcn_mbcnt_hi((unsigned int)(mask >> 32), lo);
        int pos = wcnt + (int)pr;
        if (pos < CAPW) wl_lds[g][pos] = (unsigned short)((bi << 6) | wl);
      }
      wcnt += (int)__popcll(mask);
    }
  }
  wcnt = wcnt < CAPW ? wcnt : CAPW;

  // ---- Phase B-lite: cooperatively re-evaluate only worklist batches,
  // pushing (d <= theta_q) candidates. Bit-exact: same d2pair on same S2.
  int cnt[Q];
#pragma unroll
  for (int q = 0; q < Q; ++q) cnt[q] = 0;

  for (int base = 0; base < wcnt; base += 64) {
    int ii = base + wl;
    bool val = ii < wcnt;
    int e = wl_lds[g][val ? ii : 0];
    int bi = e >> 6, src = e & 63;
#pragma unroll
    for (int hf = 0; hf < 4; ++hf) {
      S2 sv[4];
#pragma unroll
      for (int c = 0; c < 4; ++c) sv[c] = s2[(bi * 16 + hf * 4 + c) * TQ + src];
#pragma unroll
      for (int p = 0; p < 2; ++p) {
#pragma unroll
        for (int c = 0; c < 4; ++c) {
          v2f acc = d2pair(sv[c], bmx[p], bmy[p], bmz[p]);
#pragma unroll
          for (int ee = 0; ee < 2; ++ee) {
            const int q = 2 * p + ee;
            float d = ee ? acc.y : acc.x;
            bool hit = val && (d <= theta[q]);
            unsigned long long mask = __ballot(hit);
            if (mask != 0) {                 // uniform branch, mostly skipped
              const int qq = q * GROUPS + g;
              int bs = cnt[q];
              if (hit) {
                unsigned int lo = __builtin_amdgcn_mbcnt_lo((unsigned int)mask, 0u);
                unsigned int pr = __builtin_amdgcn_mbcnt_hi((unsigned int)(mask >> 32), lo);
                int pos = bs + (int)pr;
                if (pos < CAP)
                  buf[qq][pos] = (unsigned short)((bi * 16 + hf * 4 + c) * TQ + src);
              }
              cnt[q] = bs + (int)__popcll(mask);
            }
          }
        }
      }
    }
  }

  // ---- Phase C (R12-verbatim): exact selection, lex (d2,idx) = stable top_k.
#pragma unroll
  for (int q = 0; q < Q; ++q) {
    const int qq = q * GROUPS + g;
    int c = cnt[q];
    c = c < CAP ? c : CAP;

    bool v = wl < c;
    int ide = (int)buf[qq][v ? wl : 0];
    float4 se = s4[ide];
    float d2e = v ? d2of(se, m2x[q], m2y[q], m2z[q]) : INFINITY;
    ide = v ? ide : 0x7fffffff;

    int rank = 0;
    for (int f = 0; f < c; ++f) {
      float df = __shfl(d2e, f, 64);
      int jf = __shfl(ide, f, 64);
      rank += ((df < d2e) || (df == d2e && jf < ide)) ? 1 : 0;
    }

    // center = rank 0 (exists, unique): ballot + shfl its index.
    unsigned long long cb = __ballot(v && rank == 0);
    int cl = (int)__builtin_ctzll(cb);
    int ci = __shfl(ide, cl, 64);
    float4 cc = s4[ci];
    float px = -0.5f * m2x[q], py = -0.5f * m2y[q], pz = -0.5f * m2z[q];
    float vx = px - cc.x, vy = py - cc.y, vz = pz - cc.z;

    // edges = ranks 1..10 (exactly 10 since c >= 11).
    // sq = (dot(v,e) - |e|^2/2)^2 / |e|^2
    bool isedge = v && (rank >= 1) && (rank <= 10);
    float ex = se.x - cc.x, ey = se.y - cc.y, ez = se.z - cc.z;
    float el2 = ex * ex;
    el2 = fmaf(ey, ey, el2);
    el2 = fmaf(ez, ez, el2);
    float dv = vx * ex;
    dv = fmaf(vy, ey, dv);
    dv = fmaf(vz, ez, dv);
    float tt = fmaf(-0.5f, el2, dv);
    float sq = tt * tt * __builtin_amdgcn_rcpf(el2);
    float best = isedge ? sq : INFINITY;
#pragma unroll
    for (int lvl = 1; lvl <= 32; lvl <<= 1) {
      best = fminf(best, __shfl_xor(best, lvl));
    }
    if (wl == 0) out[(size_t)b * N + (tile * QPB + q * GROUPS + g)] = best;
  }
}

extern "C" void kernel_launch(void* const* d_in, const int* in_sizes, int n_in,
                              void* d_out, int out_size, void* d_ws, size_t ws_size,
                              hipStream_t stream) {
  const float* points = (const float*)d_in[0];
  const float* spoints = (const float*)d_in[1];
  float* out = (float*)d_out;
  (void)in_sizes; (void)n_in; (void)out_size; (void)d_ws; (void)ws_size;
  voroloss_kernel<<<dim3(B * (N / QPB)), dim3(BLOCK), 0, stream>>>(points, spoints, out);
}